// Round 4
// baseline (359.428 us; speedup 1.0000x reference)
//
#include <hip/hip_runtime.h>
#include <hip/hip_bf16.h>

#define BATCH 4096
#define TT 512
#define HH 64
#define BT 16      // two independent 8-row sets per block: P = rows 0..7, Q = rows 8..15
#define XS 516     // x_s row stride in floats
#define HS 72      // h buffer row stride in bf16

typedef __attribute__((ext_vector_type(8))) short short8;
typedef __attribute__((ext_vector_type(4))) float floatx4;
typedef __attribute__((ext_vector_type(2))) float float2v;

__device__ __forceinline__ unsigned short f2bf(float f) {   // RNE f32->bf16 (weights, one-time)
    unsigned u = __float_as_uint(f);
    u = u + 0x7FFFu + ((u >> 16) & 1u);
    return (unsigned short)(u >> 16);
}

// R19: dual-set alternating bodies, NO fences, cross-body read hoisting.
// R15 (951 cyc/step/16rows-per-CU) loses ~340 cyc/step to naked latency:
// post-barrier ds_read (~120) + MFMA dep chains + barrier bubbles, only
// stochastically hidden by phase-locked TLP. R16 proved the dual-set idea but
// strangled it with sched_barrier(0) fences (slack 672). This version:
// body(set S) = [issue ds_read of OTHER set's frags; INIT_S; MFMA_S (a0 x4
// then a1 x4, no dep pairs); ACT_S; write h_S; barrier]. Each ds_read is
// issued at a body top and force-drained at that body's end (compiler's
// pre-barrier s_waitcnt), so its latency hides under ~300 cyc of this body's
// MFMA+ACT, and the frags are consumed from registers one body later.
// Deterministic hiding — no reliance on wave phase. Per-row instruction
// counts identical to R15 (same float2v ACT, 8 MFMAs per 8 rows).
__global__ __launch_bounds__(256, 1) void lstm_kernel(
    const float* __restrict__ x, const float* __restrict__ W_ih,
    const float* __restrict__ W_hh, const float* __restrict__ b_ih,
    const float* __restrict__ b_hh, const float* __restrict__ W_out,
    const float* __restrict__ b_out, float* __restrict__ out)
{
    __shared__ __align__(16) float x_s[BT * XS];             // 33 KB
    __shared__ __align__(16) unsigned short hP[16 * HS];     // set P h(k); rows 4q+2,4q+3 stay 0
    __shared__ __align__(16) unsigned short hQ[16 * HS];     // set Q h(k)
    __shared__ __align__(16) float hf[BT * 65];

    const int tid = threadIdx.x;
    const int w = tid >> 6;       // wave 0..3 -> gate col-tiles {w,w+4,w+8,w+12}
    const int l = tid & 63;
    const int q = l >> 4;
    const int c = l & 15;
    const int n = 16 * w + c;     // hidden index this lane activates
    const int bbase = blockIdx.x * BT;

    // stage x[bbase..bbase+15][0..511] into LDS, coalesced float4 (2048 float4s)
    for (int i = 0; i < 8; ++i) {
        int flat = i * 256 + tid;
        int row = flat >> 7, c4 = flat & 127;
        const float4* xg = reinterpret_cast<const float4*>(x + (size_t)(bbase + row) * TT);
        float4 v = xg[c4];
        *reinterpret_cast<float4*>(&x_s[row * XS + c4 * 4]) = v;
    }
    for (int i = tid; i < 16 * HS; i += 256) { hP[i] = 0; hQ[i] = 0; }

    const float L1 = 1.44269504089f;      // log2(e)
    const float L2 = 2.88539008178f;      // 2*log2(e)

    // persistent B-fragments, PRE-SCALED: t=0(i),1(f),3(o): -log2e ; t=2(g): +2log2e
    // shared by both sets (same weights)
    short8 bfr[4][2];
    float2v wih2[4], bb2[4];
    for (int t = 0; t < 4; ++t) {
        float sc = (t == 2) ? L2 : -L1;
        int g = 64 * t + n;
        float wv = W_ih[g] * sc;
        float bv = (b_ih[g] + b_hh[g]) * sc;
        wih2[t] = float2v{wv, wv};
        bb2[t] = float2v{bv, bv};
        for (int ks = 0; ks < 2; ++ks) {
            const float* wp = W_hh + g * 64 + ks * 32 + q * 8;
            short8 v;
            #pragma unroll
            for (int j = 0; j < 8; ++j) v[j] = (short)f2bf(wp[j] * sc);
            bfr[t][ks] = v;
        }
    }

    float2v cP2 = {0.f, 0.f}, cQ2 = {0.f, 0.f};   // c-state per set, rows {2q,2q+1}
    const float2v one2 = {1.f, 1.f};
    const float2v L2v = {L2, L2};

    floatx4 accP[4], accQ[4];     // slots r=2,3 face zero A-rows: init once, stay 0
    #pragma unroll
    for (int t = 0; t < 4; ++t) {
        accP[t] = floatx4{0.f, 0.f, 0.f, 0.f};
        accQ[t] = floatx4{0.f, 0.f, 0.f, 0.f};
    }

    const int aoff = c * HS + q * 8;      // A-frag LDS offset (shorts)
    const int woff = (4 * q) * HS + n;    // h write base; +HS for second row
    const float* xP0 = &x_s[(2 * q) * XS];
    const float* xP1 = &x_s[(2 * q + 1) * XS];
    const float* xQ0 = &x_s[(8 + 2 * q) * XS];
    const float* xQ1 = &x_s[(9 + 2 * q) * XS];

    // packed activation, identical math to R15
    #define ACTP(ACC, CST, HV) do {                                             \
        float2v ei2, ef2, eg2, eo2;                                             \
        ei2.x = __builtin_amdgcn_exp2f(ACC[0][0]);                              \
        ei2.y = __builtin_amdgcn_exp2f(ACC[0][1]);                              \
        ef2.x = __builtin_amdgcn_exp2f(ACC[1][0]);                              \
        ef2.y = __builtin_amdgcn_exp2f(ACC[1][1]);                              \
        eg2.x = __builtin_amdgcn_exp2f(ACC[2][0]);                              \
        eg2.y = __builtin_amdgcn_exp2f(ACC[2][1]);                              \
        eo2.x = __builtin_amdgcn_exp2f(ACC[3][0]);                              \
        eo2.y = __builtin_amdgcn_exp2f(ACC[3][1]);                              \
        float2v pf2 = ef2 + one2;                                               \
        float2v pg2 = (ei2 + one2) * (eg2 + one2);                              \
        float2v d2 = pf2 * pg2;                                                 \
        float rd = __builtin_amdgcn_rcpf(d2.x * d2.y);                          \
        float2v num2 = (CST) * pg2 + (eg2 - one2) * pf2;                        \
        float2v dsw = {d2.y, d2.x};                                             \
        CST = num2 * dsw * rd;                                                  \
        float2v l2c = (CST) * L2v;                                              \
        float2v ec2;                                                            \
        ec2.x = __builtin_amdgcn_exp2f(l2c.x);                                  \
        ec2.y = __builtin_amdgcn_exp2f(l2c.y);                                  \
        float2v e2 = (eo2 + one2) * (ec2 + one2);                               \
        float re = __builtin_amdgcn_rcpf(e2.x * e2.y);                          \
        float2v esw = {e2.y, e2.x};                                             \
        HV = (ec2 - one2) * esw * re;                                           \
    } while (0)

    #define INIT2(ACC, X01) do {                                                \
        _Pragma("unroll")                                                       \
        for (int t = 0; t < 4; ++t) {                                           \
            float2v a2 = (X01) * wih2[t] + bb2[t];                              \
            ACC[t][0] = a2.x; ACC[t][1] = a2.y;                                 \
        }                                                                       \
    } while (0)

    // a0 group then a1 group: 4 independent chains back-to-back, no dep pairs
    #define MFMA8(ACC, A0, A1) do {                                             \
        ACC[0] = __builtin_amdgcn_mfma_f32_16x16x32_bf16(A0, bfr[0][0], ACC[0], 0, 0, 0); \
        ACC[1] = __builtin_amdgcn_mfma_f32_16x16x32_bf16(A0, bfr[1][0], ACC[1], 0, 0, 0); \
        ACC[2] = __builtin_amdgcn_mfma_f32_16x16x32_bf16(A0, bfr[2][0], ACC[2], 0, 0, 0); \
        ACC[3] = __builtin_amdgcn_mfma_f32_16x16x32_bf16(A0, bfr[3][0], ACC[3], 0, 0, 0); \
        ACC[0] = __builtin_amdgcn_mfma_f32_16x16x32_bf16(A1, bfr[0][1], ACC[0], 0, 0, 0); \
        ACC[1] = __builtin_amdgcn_mfma_f32_16x16x32_bf16(A1, bfr[1][1], ACC[1], 0, 0, 0); \
        ACC[2] = __builtin_amdgcn_mfma_f32_16x16x32_bf16(A1, bfr[2][1], ACC[2], 0, 0, 0); \
        ACC[3] = __builtin_amdgcn_mfma_f32_16x16x32_bf16(A1, bfr[3][1], ACC[3], 0, 0, 0); \
    } while (0)

    __syncthreads();   // staging + zeroed h buffers visible

    // frags_P(-1) = zeros (h(-1)=0): read once; loop invariant established
    short8 fp0 = *reinterpret_cast<const short8*>(hP + aoff);
    short8 fp1 = *reinterpret_cast<const short8*>(hP + aoff + 32);

    float2v xp01 = {xP0[0], xP1[0]};
    float2v xq01 = {xQ0[0], xQ1[0]};

    for (int k = 0; k < 511; ++k) {
        // ================= P body: step k for set P =================
        // issue Q frags read (hQ(k-1), published by prev B2 / initial barrier);
        // latency hides under this whole body, drained at B1.
        short8 fq0 = *reinterpret_cast<const short8*>(hQ + aoff);
        short8 fq1 = *reinterpret_cast<const short8*>(hQ + aoff + 32);

        INIT2(accP, xp01);
        MFMA8(accP, fp0, fp1);
        float2v hvP;
        ACTP(accP, cP2, hvP);
        {
            __hip_bfloat162 hpk = __float22bfloat162_rn(float2{hvP.x, hvP.y});
            hP[woff]      = *reinterpret_cast<unsigned short*>(&hpk.x);
            hP[woff + HS] = *reinterpret_cast<unsigned short*>(&hpk.y);
        }
        xp01 = float2v{xP0[k + 1], xP1[k + 1]};   // hoist x_P(k+1)
        __syncthreads();                           // B1: publishes hP(k)

        // ================= Q body: step k for set Q =================
        // issue P frags read (hP(k), just published); hides under this body.
        fp0 = *reinterpret_cast<const short8*>(hP + aoff);
        fp1 = *reinterpret_cast<const short8*>(hP + aoff + 32);

        INIT2(accQ, xq01);
        MFMA8(accQ, fq0, fq1);
        float2v hvQ;
        ACTP(accQ, cQ2, hvQ);
        {
            __hip_bfloat162 hpk = __float22bfloat162_rn(float2{hvQ.x, hvQ.y});
            hQ[woff]      = *reinterpret_cast<unsigned short*>(&hpk.x);
            hQ[woff + HS] = *reinterpret_cast<unsigned short*>(&hpk.y);
        }
        xq01 = float2v{xQ0[k + 1], xQ1[k + 1]};   // hoist x_Q(k+1)
        __syncthreads();                           // B2: publishes hQ(k)
    }

    // ================= tails: step 511, no h write =================
    {
        // issue Q frags (hQ(510), published by final B2) early; hide under P tail
        short8 fq0 = *reinterpret_cast<const short8*>(hQ + aoff);
        short8 fq1 = *reinterpret_cast<const short8*>(hQ + aoff + 32);

        INIT2(accP, xp01);                  // xp01 = x_P(511)
        MFMA8(accP, fp0, fp1);              // fp = hP(510), read in last Q body
        float2v hvP;
        ACTP(accP, cP2, hvP);
        hf[(2 * q) * 65 + n] = hvP.x;
        hf[(2 * q + 1) * 65 + n] = hvP.y;

        INIT2(accQ, xq01);                  // xq01 = x_Q(511)
        MFMA8(accQ, fq0, fq1);
        float2v hvQ;
        ACTP(accQ, cQ2, hvQ);
        hf[(8 + 2 * q) * 65 + n] = hvQ.x;
        hf[(9 + 2 * q) * 65 + n] = hvQ.y;
    }
    __syncthreads();

    // head: out[b][o] = sum_n hf[b][n]*W_out[o][n] + b_out[o]
    if (tid < BT * 3) {
        int row = tid / 3, o = tid % 3;
        float s = b_out[o];
        #pragma unroll 8
        for (int kk = 0; kk < HH; ++kk) s = fmaf(hf[row * 65 + kk], W_out[o * 64 + kk], s);
        out[(size_t)(bbase + row) * 3 + o] = s;
    }
    #undef ACTP
    #undef INIT2
    #undef MFMA8
}

extern "C" void kernel_launch(void* const* d_in, const int* in_sizes, int n_in,
                              void* d_out, int out_size, void* d_ws, size_t ws_size,
                              hipStream_t stream) {
    const float* x     = (const float*)d_in[0];
    const float* W_ih  = (const float*)d_in[1];
    const float* W_hh  = (const float*)d_in[2];
    const float* b_ih  = (const float*)d_in[3];
    const float* b_hh  = (const float*)d_in[4];
    const float* W_out = (const float*)d_in[5];
    const float* b_out = (const float*)d_in[6];
    float* out = (float*)d_out;
    hipLaunchKernelGGL(lstm_kernel, dim3(BATCH / BT), dim3(256), 0, stream,
                       x, W_ih, W_hh, b_ih, b_hh, W_out, b_out, out);
}

// Round 5
// 250.711 us; speedup vs baseline: 1.4336x; 1.4336x over previous
//
#include <hip/hip_runtime.h>
#include <hip/hip_bf16.h>

#define BATCH 4096
#define TT 512
#define HH 64
#define BT 8       // batch rows per block; batch j at tile row 4*(j>>1)+(j&1) -> valid C/D slots r=0,1
#define XS 516     // x_s row stride in floats
#define HS 72      // h buffer row stride in bf16

typedef __attribute__((ext_vector_type(8))) short short8;
typedef __attribute__((ext_vector_type(4))) float floatx4;
typedef __attribute__((ext_vector_type(2))) float float2v;

__device__ __forceinline__ unsigned short f2bf(float f) {   // RNE f32->bf16 (weights, one-time)
    unsigned u = __float_as_uint(f);
    u = u + 0x7FFFu + ((u >> 16) & 1u);
    return (unsigned short)(u >> 16);
}

// R20 = R15 (best, 203 us device) + ONE isolated chain trim: MFMA block
// re-grouped from 4 dependent a0->a1 pairs into a0 x4 then a1 x4 (4
// independent chains per half; second half's accumulator stalls overlap the
// first half's pipe drain). Everything else byte-identical to R15.
// Context: R16-R19 proved (a) any 1-wave/SIMD structure loses ~60% to the
// exposed serial chain, (b) wave-phase and emission-order tricks at 2
// waves/SIMD are neutral-to-negative. R15's wall 951 = issue floor ~505
// (trans 384 at the 5exp+0.5rcp/cell algebraic floor + ~120 pk VALU) +
// exposed chain ~360 (ds_read 120, barrier ~100, MFMA deps ~60, ACT tail
// ~80) + ~90 residual. This patch attacks the ~60 of MFMA deps; it is the
// last unisolated item.
__global__ __launch_bounds__(256, 2) void lstm_kernel(
    const float* __restrict__ x, const float* __restrict__ W_ih,
    const float* __restrict__ W_hh, const float* __restrict__ b_ih,
    const float* __restrict__ b_hh, const float* __restrict__ W_out,
    const float* __restrict__ b_out, float* __restrict__ out)
{
    __shared__ __align__(16) float x_s[BT * XS];             // 16.5 KB
    __shared__ __align__(16) unsigned short hb0[16 * HS];    // h_k, k even; rows m&2 stay 0
    __shared__ __align__(16) unsigned short hb1[16 * HS];    // h_k, k odd
    __shared__ __align__(16) float hf[BT * 65];

    const int tid = threadIdx.x;
    const int w = tid >> 6;       // wave 0..3 -> gate col-tiles {w,w+4,w+8,w+12}
    const int l = tid & 63;
    const int q = l >> 4;
    const int c = l & 15;
    const int n = 16 * w + c;     // hidden index this lane activates
    const int bbase = blockIdx.x * BT;

    // stage x[bbase..bbase+7][0..511] into LDS, coalesced float4
    for (int i = 0; i < 4; ++i) {
        int flat = i * 256 + tid;              // 1024 float4s
        int row = flat >> 7, c4 = flat & 127;
        const float4* xg = reinterpret_cast<const float4*>(x + (size_t)(bbase + row) * TT);
        float4 v = xg[c4];
        *reinterpret_cast<float4*>(&x_s[row * XS + c4 * 4]) = v;
    }
    for (int i = tid; i < 16 * HS; i += 256) { hb0[i] = 0; hb1[i] = 0; }

    const float L1 = 1.44269504089f;      // log2(e)
    const float L2 = 2.88539008178f;      // 2*log2(e)

    // persistent B-fragments, PRE-SCALED: t=0(i),1(f),3(o): -log2e ; t=2(g): +2log2e
    short8 bfr[4][2];
    float2v wih2[4], bb2[4];              // broadcast pairs for pk_fma acc-init
    for (int t = 0; t < 4; ++t) {
        float sc = (t == 2) ? L2 : -L1;
        int g = 64 * t + n;
        float wv = W_ih[g] * sc;
        float bv = (b_ih[g] + b_hh[g]) * sc;
        wih2[t] = float2v{wv, wv};
        bb2[t] = float2v{bv, bv};
        for (int ks = 0; ks < 2; ++ks) {
            const float* wp = W_hh + g * 64 + ks * 32 + q * 8;
            short8 v;
            #pragma unroll
            for (int j = 0; j < 8; ++j) v[j] = (short)f2bf(wp[j] * sc);
            bfr[t][ks] = v;
        }
    }

    float2v cst2 = {0.f, 0.f};    // c-state, batch rows {2q, 2q+1}, hidden n
    float2v hv2 = {0.f, 0.f};     // current h (register)
    const float2v one2 = {1.f, 1.f};
    const float2v L2v = {L2, L2};

    floatx4 acc[4];               // slots r=2,3 face zero A-rows: init once, stay 0
    #pragma unroll
    for (int t = 0; t < 4; ++t) acc[t] = floatx4{0.f, 0.f, 0.f, 0.f};

    const int aoff = c * HS + q * 8;      // A-frag LDS offset (shorts)
    const int woff = (4 * q) * HS + n;    // h write base; +HS for cell 1
    const float* xrowA = &x_s[(2 * q) * XS];
    const float* xrowB = &x_s[(2 * q + 1) * XS];

    __syncthreads();   // staging + zeroed h0 visible

    // Prologue: gates(0) = x_proj only (h(-1)=0 -> no MFMA needed)
    {
        float2v x01 = {xrowA[0], xrowB[0]};
        #pragma unroll
        for (int t = 0; t < 4; ++t) {
            float2v a2 = x01 * wih2[t] + bb2[t];
            acc[t][0] = a2.x; acc[t][1] = a2.y;
        }
    }

    // packed act: 10 scalar exp2 -> float2v algebra (pk ops) -> 2 scalar rcp
    #define ACTP() do {                                                         \
        float2v ei2, ef2, eg2, eo2;                                             \
        ei2.x = __builtin_amdgcn_exp2f(acc[0][0]);                              \
        ei2.y = __builtin_amdgcn_exp2f(acc[0][1]);                              \
        ef2.x = __builtin_amdgcn_exp2f(acc[1][0]);                              \
        ef2.y = __builtin_amdgcn_exp2f(acc[1][1]);                              \
        eg2.x = __builtin_amdgcn_exp2f(acc[2][0]);                              \
        eg2.y = __builtin_amdgcn_exp2f(acc[2][1]);                              \
        eo2.x = __builtin_amdgcn_exp2f(acc[3][0]);                              \
        eo2.y = __builtin_amdgcn_exp2f(acc[3][1]);                              \
        float2v pf2 = ef2 + one2;                                               \
        float2v pg2 = (ei2 + one2) * (eg2 + one2);                              \
        float2v d2 = pf2 * pg2;                                                 \
        float rd = __builtin_amdgcn_rcpf(d2.x * d2.y);                          \
        float2v num2 = cst2 * pg2 + (eg2 - one2) * pf2;                         \
        float2v dsw = {d2.y, d2.x};                                             \
        cst2 = num2 * dsw * rd;                                                 \
        float2v l2c = cst2 * L2v;                                               \
        float2v ec2;                                                            \
        ec2.x = __builtin_amdgcn_exp2f(l2c.x);                                  \
        ec2.y = __builtin_amdgcn_exp2f(l2c.y);                                  \
        float2v e2 = (eo2 + one2) * (ec2 + one2);                               \
        float re = __builtin_amdgcn_rcpf(e2.x * e2.y);                          \
        float2v esw = {e2.y, e2.x};                                             \
        hv2 = (ec2 - one2) * esw * re;                                          \
    } while (0)

    // one pipelined step: act(k) -> packed h write -> barrier -> frag read +
    // MFMA(k+1). dst is a compile-time constant pointer at each call site.
    auto step = [&](int k, unsigned short* dst) {
        ACTP();
        // one v_cvt_pk_bf16_f32; stores lower to b16, upper to b16_d16_hi
        __hip_bfloat162 hpk = __float22bfloat162_rn(float2{hv2.x, hv2.y});
        dst[woff]      = *reinterpret_cast<unsigned short*>(&hpk.x);
        dst[woff + HS] = *reinterpret_cast<unsigned short*>(&hpk.y);

        // hoist x(k+1) LDS reads: latency hides under the barrier
        float2v x01 = {xrowA[k + 1], xrowB[k + 1]};

        __syncthreads();

        short8 a0 = *reinterpret_cast<const short8*>(dst + aoff);
        short8 a1 = *reinterpret_cast<const short8*>(dst + aoff + 32);
        #pragma unroll
        for (int t = 0; t < 4; ++t) {
            float2v a2 = x01 * wih2[t] + bb2[t];
            acc[t][0] = a2.x; acc[t][1] = a2.y;
        }
        // a0 group then a1 group: 4 independent chains per half, no dep pairs
        acc[0] = __builtin_amdgcn_mfma_f32_16x16x32_bf16(a0, bfr[0][0], acc[0], 0, 0, 0);
        acc[1] = __builtin_amdgcn_mfma_f32_16x16x32_bf16(a0, bfr[1][0], acc[1], 0, 0, 0);
        acc[2] = __builtin_amdgcn_mfma_f32_16x16x32_bf16(a0, bfr[2][0], acc[2], 0, 0, 0);
        acc[3] = __builtin_amdgcn_mfma_f32_16x16x32_bf16(a0, bfr[3][0], acc[3], 0, 0, 0);
        acc[0] = __builtin_amdgcn_mfma_f32_16x16x32_bf16(a1, bfr[0][1], acc[0], 0, 0, 0);
        acc[1] = __builtin_amdgcn_mfma_f32_16x16x32_bf16(a1, bfr[1][1], acc[1], 0, 0, 0);
        acc[2] = __builtin_amdgcn_mfma_f32_16x16x32_bf16(a1, bfr[2][1], acc[2], 0, 0, 0);
        acc[3] = __builtin_amdgcn_mfma_f32_16x16x32_bf16(a1, bfr[3][1], acc[3], 0, 0, 0);
    };

    // steps 0..510 pipelined (write h(k), issue MFMA(k+1)); manual 2x unroll
    for (int k = 0; k < 510; k += 2) {
        step(k, hb0);         // even k -> hb0
        step(k + 1, hb1);     // odd  k -> hb1
    }
    step(510, hb0);

    // ---- final act(511) ----
    ACTP();

    hf[(2 * q) * 65 + n] = hv2.x;
    hf[(2 * q + 1) * 65 + n] = hv2.y;
    __syncthreads();

    // head: out[b][o] = sum_n hf[b][n]*W_out[o][n] + b_out[o]
    if (tid < BT * 3) {
        int row = tid / 3, o = tid % 3;
        float s = b_out[o];
        #pragma unroll 8
        for (int k = 0; k < HH; ++k) s = fmaf(hf[row * 65 + k], W_out[o * 64 + k], s);
        out[(size_t)(bbase + row) * 3 + o] = s;
    }
    #undef ACTP
}

extern "C" void kernel_launch(void* const* d_in, const int* in_sizes, int n_in,
                              void* d_out, int out_size, void* d_ws, size_t ws_size,
                              hipStream_t stream) {
    const float* x     = (const float*)d_in[0];
    const float* W_ih  = (const float*)d_in[1];
    const float* W_hh  = (const float*)d_in[2];
    const float* b_ih  = (const float*)d_in[3];
    const float* b_hh  = (const float*)d_in[4];
    const float* W_out = (const float*)d_in[5];
    const float* b_out = (const float*)d_in[6];
    float* out = (float*)d_out;
    hipLaunchKernelGGL(lstm_kernel, dim3(BATCH / BT), dim3(256), 0, stream,
                       x, W_ih, W_hh, b_ih, b_hh, W_out, b_out, out);
}

// Round 6
// 248.017 us; speedup vs baseline: 1.4492x; 1.0109x over previous
//
#include <hip/hip_runtime.h>
#include <hip/hip_bf16.h>

#define BATCH 4096
#define TT 512
#define HH 64
#define BT 8       // batch rows per block; batch j at tile row 4*(j>>1)+(j&1) -> valid C/D slots r=0,1
#define XS 516     // x_s row stride in floats
#define HS 72      // h buffer row stride in bf16

typedef __attribute__((ext_vector_type(8))) short short8;
typedef __attribute__((ext_vector_type(4))) float floatx4;
typedef __attribute__((ext_vector_type(2))) float float2v;

__device__ __forceinline__ unsigned short f2bf(float f) {   // RNE f32->bf16 (weights, one-time)
    unsigned u = __float_as_uint(f);
    u = u + 0x7FFFu + ((u >> 16) & 1u);
    return (unsigned short)(u >> 16);
}

// R21 = R15 restored verbatim (best harness-verified: 247.0 us / ~203 us
// device on the round-0 container). Serves as the drift control: R17
// (R15 + one-time prologue ticket) and R20 (R15 + MFMA regroup) both
// measured 214-216 us on later containers vs R15's 203-206 on round 0 —
// two independent R15+epsilon kernels at the same offset imply ~5%
// container/clock drift, not real regressions.
// Final accounting (cross-validated by R16-R20): wall 951 cyc/step =
// VALU issue floor ~505 (trans 384 = 24 cyc/row, algebraic floor at
// 5 exp + 0.5 rcp per cell; + ~120 packed algebra) + MFMA issue 310
// (50% row-util; only fix is BT=16 which forces 1 wave/SIMD and loses
// 60% to the exposed chain) + exposed chain ~136 (post-barrier ds_read,
// barrier, ACT tail). All overlap/chain levers isolated and eliminated:
// in-wave anti-phase (R16: +68%), sleep offset (R17: neutral-),
// emission weave (R18: +14%), fence-free dual-set (R19: +52%),
// MFMA regroup (R20: neutral). This is the structural optimum of the
// 2-wave/SIMD barrier-exchange topology.
__global__ __launch_bounds__(256, 2) void lstm_kernel(
    const float* __restrict__ x, const float* __restrict__ W_ih,
    const float* __restrict__ W_hh, const float* __restrict__ b_ih,
    const float* __restrict__ b_hh, const float* __restrict__ W_out,
    const float* __restrict__ b_out, float* __restrict__ out)
{
    __shared__ __align__(16) float x_s[BT * XS];             // 16.5 KB
    __shared__ __align__(16) unsigned short hb0[16 * HS];    // h_k, k even; rows m&2 stay 0
    __shared__ __align__(16) unsigned short hb1[16 * HS];    // h_k, k odd
    __shared__ __align__(16) float hf[BT * 65];

    const int tid = threadIdx.x;
    const int w = tid >> 6;       // wave 0..3 -> gate col-tiles {w,w+4,w+8,w+12}
    const int l = tid & 63;
    const int q = l >> 4;
    const int c = l & 15;
    const int n = 16 * w + c;     // hidden index this lane activates
    const int bbase = blockIdx.x * BT;

    // stage x[bbase..bbase+7][0..511] into LDS, coalesced float4
    for (int i = 0; i < 4; ++i) {
        int flat = i * 256 + tid;              // 1024 float4s
        int row = flat >> 7, c4 = flat & 127;
        const float4* xg = reinterpret_cast<const float4*>(x + (size_t)(bbase + row) * TT);
        float4 v = xg[c4];
        *reinterpret_cast<float4*>(&x_s[row * XS + c4 * 4]) = v;
    }
    for (int i = tid; i < 16 * HS; i += 256) { hb0[i] = 0; hb1[i] = 0; }

    const float L1 = 1.44269504089f;      // log2(e)
    const float L2 = 2.88539008178f;      // 2*log2(e)

    // persistent B-fragments, PRE-SCALED: t=0(i),1(f),3(o): -log2e ; t=2(g): +2log2e
    short8 bfr[4][2];
    float2v wih2[4], bb2[4];              // broadcast pairs for pk_fma acc-init
    for (int t = 0; t < 4; ++t) {
        float sc = (t == 2) ? L2 : -L1;
        int g = 64 * t + n;
        float wv = W_ih[g] * sc;
        float bv = (b_ih[g] + b_hh[g]) * sc;
        wih2[t] = float2v{wv, wv};
        bb2[t] = float2v{bv, bv};
        for (int ks = 0; ks < 2; ++ks) {
            const float* wp = W_hh + g * 64 + ks * 32 + q * 8;
            short8 v;
            #pragma unroll
            for (int j = 0; j < 8; ++j) v[j] = (short)f2bf(wp[j] * sc);
            bfr[t][ks] = v;
        }
    }

    float2v cst2 = {0.f, 0.f};    // c-state, batch rows {2q, 2q+1}, hidden n
    float2v hv2 = {0.f, 0.f};     // current h (register)
    const float2v one2 = {1.f, 1.f};
    const float2v L2v = {L2, L2};

    floatx4 acc[4];               // slots r=2,3 face zero A-rows: init once, stay 0
    #pragma unroll
    for (int t = 0; t < 4; ++t) acc[t] = floatx4{0.f, 0.f, 0.f, 0.f};

    const int aoff = c * HS + q * 8;      // A-frag LDS offset (shorts)
    const int woff = (4 * q) * HS + n;    // h write base; +HS for cell 1
    const float* xrowA = &x_s[(2 * q) * XS];
    const float* xrowB = &x_s[(2 * q + 1) * XS];

    __syncthreads();   // staging + zeroed h0 visible

    // Prologue: gates(0) = x_proj only (h(-1)=0 -> no MFMA needed)
    {
        float2v x01 = {xrowA[0], xrowB[0]};
        #pragma unroll
        for (int t = 0; t < 4; ++t) {
            float2v a2 = x01 * wih2[t] + bb2[t];
            acc[t][0] = a2.x; acc[t][1] = a2.y;
        }
    }

    // packed act: 10 scalar exp2 -> float2v algebra (pk ops) -> 2 scalar rcp
    #define ACTP() do {                                                         \
        float2v ei2, ef2, eg2, eo2;                                             \
        ei2.x = __builtin_amdgcn_exp2f(acc[0][0]);                              \
        ei2.y = __builtin_amdgcn_exp2f(acc[0][1]);                              \
        ef2.x = __builtin_amdgcn_exp2f(acc[1][0]);                              \
        ef2.y = __builtin_amdgcn_exp2f(acc[1][1]);                              \
        eg2.x = __builtin_amdgcn_exp2f(acc[2][0]);                              \
        eg2.y = __builtin_amdgcn_exp2f(acc[2][1]);                              \
        eo2.x = __builtin_amdgcn_exp2f(acc[3][0]);                              \
        eo2.y = __builtin_amdgcn_exp2f(acc[3][1]);                              \
        float2v pf2 = ef2 + one2;                                               \
        float2v pg2 = (ei2 + one2) * (eg2 + one2);                              \
        float2v d2 = pf2 * pg2;                                                 \
        float rd = __builtin_amdgcn_rcpf(d2.x * d2.y);                          \
        float2v num2 = cst2 * pg2 + (eg2 - one2) * pf2;                         \
        float2v dsw = {d2.y, d2.x};                                             \
        cst2 = num2 * dsw * rd;                                                 \
        float2v l2c = cst2 * L2v;                                               \
        float2v ec2;                                                            \
        ec2.x = __builtin_amdgcn_exp2f(l2c.x);                                  \
        ec2.y = __builtin_amdgcn_exp2f(l2c.y);                                  \
        float2v e2 = (eo2 + one2) * (ec2 + one2);                               \
        float re = __builtin_amdgcn_rcpf(e2.x * e2.y);                          \
        float2v esw = {e2.y, e2.x};                                             \
        hv2 = (ec2 - one2) * esw * re;                                          \
    } while (0)

    // one pipelined step: act(k) -> packed h write -> barrier -> frag read +
    // MFMA(k+1). dst is a compile-time constant pointer at each call site.
    auto step = [&](int k, unsigned short* dst) {
        ACTP();
        // one v_cvt_pk_bf16_f32; stores lower to b16, upper to b16_d16_hi
        __hip_bfloat162 hpk = __float22bfloat162_rn(float2{hv2.x, hv2.y});
        dst[woff]      = *reinterpret_cast<unsigned short*>(&hpk.x);
        dst[woff + HS] = *reinterpret_cast<unsigned short*>(&hpk.y);

        // hoist x(k+1) LDS reads: latency hides under the barrier
        float2v x01 = {xrowA[k + 1], xrowB[k + 1]};

        __syncthreads();

        short8 a0 = *reinterpret_cast<const short8*>(dst + aoff);
        short8 a1 = *reinterpret_cast<const short8*>(dst + aoff + 32);
        #pragma unroll
        for (int t = 0; t < 4; ++t) {
            float2v a2 = x01 * wih2[t] + bb2[t];
            acc[t][0] = a2.x; acc[t][1] = a2.y;
        }
        #pragma unroll
        for (int t = 0; t < 4; ++t) {
            acc[t] = __builtin_amdgcn_mfma_f32_16x16x32_bf16(a0, bfr[t][0], acc[t], 0, 0, 0);
            acc[t] = __builtin_amdgcn_mfma_f32_16x16x32_bf16(a1, bfr[t][1], acc[t], 0, 0, 0);
        }
    };

    // steps 0..510 pipelined (write h(k), issue MFMA(k+1)); manual 2x unroll
    for (int k = 0; k < 510; k += 2) {
        step(k, hb0);         // even k -> hb0
        step(k + 1, hb1);     // odd  k -> hb1
    }
    step(510, hb0);

    // ---- final act(511) ----
    ACTP();

    hf[(2 * q) * 65 + n] = hv2.x;
    hf[(2 * q + 1) * 65 + n] = hv2.y;
    __syncthreads();

    // head: out[b][o] = sum_n hf[b][n]*W_out[o][n] + b_out[o]
    if (tid < BT * 3) {
        int row = tid / 3, o = tid % 3;
        float s = b_out[o];
        #pragma unroll 8
        for (int k = 0; k < HH; ++k) s = fmaf(hf[row * 65 + k], W_out[o * 64 + k], s);
        out[(size_t)(bbase + row) * 3 + o] = s;
    }
    #undef ACTP
}

extern "C" void kernel_launch(void* const* d_in, const int* in_sizes, int n_in,
                              void* d_out, int out_size, void* d_ws, size_t ws_size,
                              hipStream_t stream) {
    const float* x     = (const float*)d_in[0];
    const float* W_ih  = (const float*)d_in[1];
    const float* W_hh  = (const float*)d_in[2];
    const float* b_ih  = (const float*)d_in[3];
    const float* b_hh  = (const float*)d_in[4];
    const float* W_out = (const float*)d_in[5];
    const float* b_out = (const float*)d_in[6];
    float* out = (float*)d_out;
    hipLaunchKernelGGL(lstm_kernel, dim3(BATCH / BT), dim3(256), 0, stream,
                       x, W_ih, W_hh, b_ih, b_hh, W_out, b_out, out);
}